// Round 5
// baseline (310.124 us; speedup 1.0000x reference)
//
#include <hip/hip_runtime.h>
#include <stdint.h>

// D3 dispersion on MI355X (gfx950).
// Established: all float arrays fp32, ints int32, output fp32.
// The harness np reference runs fp32 with FTZ (flush-to-zero) active in the
// host process: np.exp results below 2^-126 become exactly 0. Hence the
// reference's norm==0 "exceptional" (one-hot) branch triggers iff EVERY
// masked gaussian arg < ln(2^-126) = -87.33654. GPU expf produces denormals
// (evidence: R2==R4), so we must branch on the argument, not the GPU norm:
//   marg < -87.33654 -> one-hot on max reference CN
//   else             -> gw / max(norm, 1e-30)  (FTZ-band terms are denormal
//                       on GPU -> weights <= 1.2e-8, matching ref's 0)

typedef unsigned short u16;
#define MAXZ 95
#define NREF 5
#define EXC_CUT -87.33654f   // ln(2^-126): fp32 FTZ underflow of exp

__device__ __forceinline__ float switch_fn(float d) {
    if (d < 10.0f) return 1.0f;
    float x = (12.0f - d) * 0.5f;
    return ((6.0f * x - 15.0f) * x + 10.0f) * x * x * x;
}

// Reference-faithful (fp32 + host FTZ) Gaussian weights for one atom.
__device__ __forceinline__ void calc_weights(const float* __restrict__ rcn_z,
                                             float cni, float* __restrict__ w) {
    float r[NREF], arg[NREF];
    float rmax = -1e30f, marg = -1e30f;
#pragma unroll
    for (int a = 0; a < NREF; a++) {
        r[a] = rcn_z[a];
        rmax = fmaxf(rmax, r[a]);
        float dc = r[a] - cni;
        arg[a] = (-4.0f * dc) * dc;            // mirror np's K3*dcn*dcn assoc
        if (r[a] >= 0.0f) marg = fmaxf(marg, arg[a]);
    }
    if (marg < EXC_CUT) {
        // host-FTZ norm would be exactly 0: one-hot on max reference CN
#pragma unroll
        for (int a = 0; a < NREF; a++) w[a] = (r[a] == rmax) ? 1.0f : 0.0f;
    } else {
        float g[NREF], norm = 0.0f;
#pragma unroll
        for (int a = 0; a < NREF; a++) {
            float e = (r[a] >= 0.0f) ? expf(arg[a]) : 0.0f;
            g[a] = e;
            norm += e;
        }
        float inv = 1.0f / fmaxf(norm, 1e-30f);
#pragma unroll
        for (int a = 0; a < NREF; a++) w[a] = g[a] * inv;
    }
}

// ---------------------------------------------------------------------------
__global__ __launch_bounds__(256) void prep_rcov(const float* __restrict__ rcov,
                                                 const int* __restrict__ Z,
                                                 float* __restrict__ rcovA,
                                                 int n_atoms) {
    int i = blockIdx.x * blockDim.x + threadIdx.x;
    if (i >= n_atoms) return;
    rcovA[i] = rcov[Z[i]];
}

// Repack rc6[95,95,5,5] -> fp32 tiles of 32 (128 B, two aligned lines per
// (zi,zj)) so the per-pair table gather is two aligned float4 runs.
__global__ __launch_bounds__(256) void repack_rc6(const float* __restrict__ rc6,
                                                  float* __restrict__ rc6pad,
                                                  int total) {
    int id = blockIdx.x * blockDim.x + threadIdx.x;
    if (id >= total) return;
    int tile = id >> 5;
    int slot = id & 31;
    rc6pad[id] = (slot < 25) ? rc6[(size_t)tile * 25 + slot] : 0.0f;
}

// ---------------------------------------------------------------------------
__global__ __launch_bounds__(256) void pair_cn(const float* __restrict__ dist,
                                               const float* __restrict__ rcovA,
                                               const int* __restrict__ idx_i,
                                               const int* __restrict__ idx_j,
                                               float* __restrict__ cn,
                                               int n_pairs) {
    int p = blockIdx.x * blockDim.x + threadIdx.x;
    if (p >= n_pairs) return;
    float d = dist[p];
    if (d >= 12.0f) return;                        // sw == 0
    int i = idx_i[p];
    int j = idx_j[p];
    float rij = rcovA[i] + rcovA[j];
    float sw = switch_fn(d);
    float cnij = sw / (1.0f + expf(-16.0f * (rij / d - 1.0f)));
    atomicAdd(&cn[i], cnij);
}

__global__ __launch_bounds__(256) void pair_cn_slim(const float* __restrict__ dist,
                                                    const float* __restrict__ rcov,
                                                    const int* __restrict__ Z,
                                                    const int* __restrict__ idx_i,
                                                    const int* __restrict__ idx_j,
                                                    float* __restrict__ cn,
                                                    int n_pairs) {
    int p = blockIdx.x * blockDim.x + threadIdx.x;
    if (p >= n_pairs) return;
    float d = dist[p];
    if (d >= 12.0f) return;
    int i = idx_i[p];
    int j = idx_j[p];
    float rij = rcov[Z[i]] + rcov[Z[j]];
    float sw = switch_fn(d);
    float cnij = sw / (1.0f + expf(-16.0f * (rij / d - 1.0f)));
    atomicAdd(&cn[i], cnij);
}

// ---------------------------------------------------------------------------
// Per-atom record: {w0..w4, r2r4[z], z_bits, 0} = 32 B (one cache line).
__global__ __launch_bounds__(256) void atom_weights(const float* __restrict__ rcn,
                                                    const float* __restrict__ r2r4,
                                                    const int* __restrict__ Z,
                                                    const float* __restrict__ cn,
                                                    float* __restrict__ arec,
                                                    int n_atoms) {
    int i = blockIdx.x * blockDim.x + threadIdx.x;
    if (i >= n_atoms) return;
    int z = Z[i];
    float w[NREF];
    calc_weights(rcn + (size_t)z * NREF, cn[i], w);
    float4 v0 = make_float4(w[0], w[1], w[2], w[3]);
    float4 v1 = make_float4(w[4], r2r4[z], __int_as_float(z), 0.0f);
    float4* dst = (float4*)(arec + (size_t)i * 8);
    dst[0] = v0;
    dst[1] = v1;
}

// ---------------------------------------------------------------------------
__global__ __launch_bounds__(256) void pair_energy(const float* __restrict__ dist,
                                                   const int* __restrict__ idx_i,
                                                   const int* __restrict__ idx_j,
                                                   const float* __restrict__ arec,
                                                   const float* __restrict__ rc6pad,
                                                   const float* __restrict__ s6p,
                                                   const float* __restrict__ s8p,
                                                   const float* __restrict__ a1p,
                                                   const float* __restrict__ a2p,
                                                   float* __restrict__ eout,
                                                   int n_pairs) {
    int p = blockIdx.x * blockDim.x + threadIdx.x;
    if (p >= n_pairs) return;
    float d = dist[p];
    if (d >= 12.0f) return;                        // sw == 0
    int i = idx_i[p];
    int j = idx_j[p];

    const float4* Ai = (const float4*)(arec + (size_t)i * 8);
    const float4* Aj = (const float4*)(arec + (size_t)j * 8);
    float4 ai0 = Ai[0];
    float4 ai1 = Ai[1];
    float4 aj0 = Aj[0];
    float4 aj1 = Aj[1];
    float wi[NREF] = {ai0.x, ai0.y, ai0.z, ai0.w, ai1.x};
    float wj[NREF] = {aj0.x, aj0.y, aj0.z, aj0.w, aj1.x};
    int zi = __float_as_int(ai1.z);
    int zj = __float_as_int(aj1.z);

    // two aligned 64B lines: 25 fp32 in a 32-slot tile
    const float4* T4 = (const float4*)(rc6pad + (size_t)(zi * MAXZ + zj) * 32);
    float tt[25];
#pragma unroll
    for (int k = 0; k < 6; k++) {
        float4 t = T4[k];
        tt[4 * k + 0] = t.x;
        if (4 * k + 1 < 25) tt[4 * k + 1] = t.y;
        if (4 * k + 2 < 25) tt[4 * k + 2] = t.z;
        if (4 * k + 3 < 25) tt[4 * k + 3] = t.w;
    }
    tt[24] = ((const float*)T4)[24];

    float c6 = 0.0f;
#pragma unroll
    for (int a = 0; a < NREF; a++) {
        float s = 0.0f;
#pragma unroll
        for (int b = 0; b < NREF; b++) s = fmaf(wj[b], tt[a * NREF + b], s);
        c6 = fmaf(wi[a], s, c6);
    }

    float qq = 3.0f * ai1.y * aj1.y;
    float rr = a1p[0] * sqrtf(qq) + a2p[0];
    float d2 = d * d;
    float d6 = d2 * d2 * d2;
    float d8 = d6 * d2;
    float rr2 = rr * rr;
    float rr6 = rr2 * rr2 * rr2;
    float rr8 = rr6 * rr2;
    float sw = switch_fn(d);

    float e = -0.5f * (s6p[0] * c6 / (d6 + rr6) + s8p[0] * qq * c6 / (d8 + rr8)) * sw;
    atomicAdd(&eout[i], e);
}

// slim variant: recompute weights per pair side, read rc6 directly.
__global__ __launch_bounds__(256) void pair_energy_slim(const float* __restrict__ dist,
                                                        const int* __restrict__ Z,
                                                        const int* __restrict__ idx_i,
                                                        const int* __restrict__ idx_j,
                                                        const float* __restrict__ cn,
                                                        const float* __restrict__ rcn,
                                                        const float* __restrict__ r2r4,
                                                        const float* __restrict__ rc6,
                                                        const float* __restrict__ s6p,
                                                        const float* __restrict__ s8p,
                                                        const float* __restrict__ a1p,
                                                        const float* __restrict__ a2p,
                                                        float* __restrict__ eout,
                                                        int n_pairs) {
    int p = blockIdx.x * blockDim.x + threadIdx.x;
    if (p >= n_pairs) return;
    float d = dist[p];
    if (d >= 12.0f) return;
    int i = idx_i[p];
    int j = idx_j[p];
    int zi = Z[i];
    int zj = Z[j];
    float wi[NREF], wj[NREF];
    calc_weights(rcn + (size_t)zi * NREF, cn[i], wi);
    calc_weights(rcn + (size_t)zj * NREF, cn[j], wj);

    const float* T = rc6 + (size_t)(zi * MAXZ + zj) * 25;
    float c6 = 0.0f;
#pragma unroll
    for (int a = 0; a < NREF; a++) {
        float s = 0.0f;
#pragma unroll
        for (int b = 0; b < NREF; b++) s = fmaf(wj[b], T[a * NREF + b], s);
        c6 = fmaf(wi[a], s, c6);
    }

    float qq = 3.0f * r2r4[zi] * r2r4[zj];
    float rr = a1p[0] * sqrtf(qq) + a2p[0];
    float d2 = d * d;
    float d6 = d2 * d2 * d2;
    float d8 = d6 * d2;
    float rr2 = rr * rr;
    float rr6 = rr2 * rr2 * rr2;
    float rr8 = rr6 * rr2;
    float sw = switch_fn(d);

    float e = -0.5f * (s6p[0] * c6 / (d6 + rr6) + s8p[0] * qq * c6 / (d8 + rr8)) * sw;
    atomicAdd(&eout[i], e);
}

// ---------------------------------------------------------------------------
extern "C" void kernel_launch(void* const* d_in, const int* in_sizes, int n_in,
                              void* d_out, int out_size, void* d_ws, size_t ws_size,
                              hipStream_t stream) {
    const float* dist = (const float*)d_in[0];
    const float* rcov = (const float*)d_in[1];
    const float* rcn  = (const float*)d_in[2];
    const float* rc6  = (const float*)d_in[3];
    const float* r2r4 = (const float*)d_in[4];
    const float* s6p  = (const float*)d_in[5];
    const float* s8p  = (const float*)d_in[6];
    const float* a1p  = (const float*)d_in[7];
    const float* a2p  = (const float*)d_in[8];
    const int* Z    = (const int*)d_in[9];
    const int* idxi = (const int*)d_in[10];
    const int* idxj = (const int*)d_in[11];
    float* out = (float*)d_out;

    int n_pairs = in_sizes[0];
    int n_atoms = in_sizes[9];
    int agrid = (n_atoms + 255) / 256;
    int pgrid = (n_pairs + 255) / 256;

    char* ws = (char*)d_ws;
    float* cn = (float*)ws;                                    // [0, 4n)

    hipMemsetAsync(out, 0, (size_t)n_atoms * 4, stream);       // energy accum = d_out
    hipMemsetAsync(cn, 0, (size_t)n_atoms * 4, stream);

    size_t need = (size_t)n_atoms * 40 + (size_t)MAXZ * MAXZ * 32 * 4;
    if (ws_size >= need) {
        float* rcovA = (float*)(ws + (size_t)n_atoms * 4);     // [4n, 8n)
        float* arec  = (float*)(ws + (size_t)n_atoms * 8);     // [8n, 40n)
        float* rcpad = (float*)(ws + (size_t)n_atoms * 40);    // [40n, +1155200)

        prep_rcov<<<agrid, 256, 0, stream>>>(rcov, Z, rcovA, n_atoms);
        int rc_total = MAXZ * MAXZ * 32;
        repack_rc6<<<(rc_total + 255) / 256, 256, 0, stream>>>(rc6, rcpad, rc_total);
        pair_cn<<<pgrid, 256, 0, stream>>>(dist, rcovA, idxi, idxj, cn, n_pairs);
        atom_weights<<<agrid, 256, 0, stream>>>(rcn, r2r4, Z, cn, arec, n_atoms);
        pair_energy<<<pgrid, 256, 0, stream>>>(dist, idxi, idxj, arec, rcpad,
                                               s6p, s8p, a1p, a2p, out, n_pairs);
    } else {
        pair_cn_slim<<<pgrid, 256, 0, stream>>>(dist, rcov, Z, idxi, idxj, cn, n_pairs);
        pair_energy_slim<<<pgrid, 256, 0, stream>>>(dist, Z, idxi, idxj, cn, rcn, r2r4,
                                                    rc6, s6p, s8p, a1p, a2p, out, n_pairs);
    }
}

// Round 6
// 183.124 us; speedup vs baseline: 1.6935x; 1.6935x over previous
//
#include <hip/hip_runtime.h>
#include <stdint.h>

// D3 dispersion on MI355X (gfx950).
// R5 evidence: pair kernels bound by 2M global fp32 atomics each
// (WRITE_SIZE = 2M x 32B write-through RMW). R6: counting-sort pairs by
// idx_i>>7 into 512 buckets (8B records), then per-bucket LDS accumulation
// -> zero global fp32 atomics; results written coalesced, non-atomic.
// Reference semantics (established R2-R5): fp32 storage, np reference is
// fp32 with FTZ in exp: exceptional one-hot branch iff every masked gaussian
// arg < ln(2^-126) = -87.33654.

typedef unsigned short u16;
#define MAXZ 95
#define NREF 5
#define EXC_CUT -87.33654f
#define NB  512      // buckets
#define BSH 7        // log2 atoms per bucket
#define BSZ 128      // atoms per bucket

__device__ __forceinline__ float switch_fn(float d) {
    if (d < 10.0f) return 1.0f;
    float x = (12.0f - d) * 0.5f;
    return ((6.0f * x - 15.0f) * x + 10.0f) * x * x * x;
}

__device__ __forceinline__ void calc_weights(const float* __restrict__ rcn_z,
                                             float cni, float* __restrict__ w) {
    float r[NREF], arg[NREF];
    float rmax = -1e30f, marg = -1e30f;
#pragma unroll
    for (int a = 0; a < NREF; a++) {
        r[a] = rcn_z[a];
        rmax = fmaxf(rmax, r[a]);
        float dc = r[a] - cni;
        arg[a] = (-4.0f * dc) * dc;
        if (r[a] >= 0.0f) marg = fmaxf(marg, arg[a]);
    }
    if (marg < EXC_CUT) {
#pragma unroll
        for (int a = 0; a < NREF; a++) w[a] = (r[a] == rmax) ? 1.0f : 0.0f;
    } else {
        float g[NREF], norm = 0.0f;
#pragma unroll
        for (int a = 0; a < NREF; a++) {
            float e = (r[a] >= 0.0f) ? expf(arg[a]) : 0.0f;
            g[a] = e;
            norm += e;
        }
        float inv = 1.0f / fmaxf(norm, 1e-30f);
#pragma unroll
        for (int a = 0; a < NREF; a++) w[a] = g[a] * inv;
    }
}

// ---------------------------------------------------------------------------
__global__ __launch_bounds__(256) void prep_rcov(const float* __restrict__ rcov,
                                                 const int* __restrict__ Z,
                                                 float* __restrict__ rcovA,
                                                 int n_atoms) {
    int i = blockIdx.x * blockDim.x + threadIdx.x;
    if (i >= n_atoms) return;
    rcovA[i] = rcov[Z[i]];
}

__global__ __launch_bounds__(256) void repack_rc6(const float* __restrict__ rc6,
                                                  float* __restrict__ rc6pad,
                                                  int total) {
    int id = blockIdx.x * blockDim.x + threadIdx.x;
    if (id >= total) return;
    int tile = id >> 5;
    int slot = id & 31;
    rc6pad[id] = (slot < 25) ? rc6[(size_t)tile * 25 + slot] : 0.0f;
}

// ---------------------------------------------------------------------------
// Sort stage 1: per-bucket totals (LDS histogram, one int atomic per
// nonzero (block,bucket)).
__global__ __launch_bounds__(1024) void count_pairs(const float* __restrict__ dist,
                                                    const int* __restrict__ idx_i,
                                                    uint32_t* __restrict__ totals,
                                                    int n_pairs, int chunk) {
    __shared__ uint32_t hist[NB];
    for (int t = threadIdx.x; t < NB; t += 1024) hist[t] = 0;
    __syncthreads();
    int lo = blockIdx.x * chunk;
    int hi = min(lo + chunk, n_pairs);
    for (int p = lo + (int)threadIdx.x; p < hi; p += 1024) {
        float d = dist[p];
        if (d < 12.0f) atomicAdd(&hist[((uint32_t)idx_i[p]) >> BSH], 1u);
    }
    __syncthreads();
    for (int t = threadIdx.x; t < NB; t += 1024) {
        uint32_t h = hist[t];
        if (h) atomicAdd(&totals[t], h);
    }
}

// Sort stage 2: exclusive scan of 512 totals -> gstart (fixed) + gbase (working).
__global__ __launch_bounds__(NB) void scan_buckets(const uint32_t* __restrict__ totals,
                                                   uint32_t* __restrict__ gstart,
                                                   uint32_t* __restrict__ gbase) {
    __shared__ uint32_t s[NB];
    int t = threadIdx.x;
    uint32_t mine = totals[t];
    s[t] = mine;
    __syncthreads();
    for (int off = 1; off < NB; off <<= 1) {
        uint32_t v = (t >= off) ? s[t - off] : 0u;
        __syncthreads();
        s[t] += v;
        __syncthreads();
    }
    uint32_t excl = s[t] - mine;
    gstart[t] = excl;
    gbase[t]  = excl;
}

// Sort stage 3: scatter records {d, j | (i&127)<<16} into bucket-contiguous
// storage. Blocks claim per-bucket ranges with one int atomic per
// (block,bucket); placement within range via LDS running counters.
__global__ __launch_bounds__(1024) void scatter_pairs(const float* __restrict__ dist,
                                                      const int* __restrict__ idx_i,
                                                      const int* __restrict__ idx_j,
                                                      uint32_t* __restrict__ gbase,
                                                      uint2* __restrict__ recs,
                                                      int n_pairs, int chunk) {
    __shared__ uint32_t hist[NB];
    __shared__ uint32_t run[NB];
    for (int t = threadIdx.x; t < NB; t += 1024) hist[t] = 0;
    __syncthreads();
    int lo = blockIdx.x * chunk;
    int hi = min(lo + chunk, n_pairs);
    for (int p = lo + (int)threadIdx.x; p < hi; p += 1024) {
        float d = dist[p];
        if (d < 12.0f) atomicAdd(&hist[((uint32_t)idx_i[p]) >> BSH], 1u);
    }
    __syncthreads();
    for (int t = threadIdx.x; t < NB; t += 1024) {
        uint32_t h = hist[t];
        run[t] = h ? atomicAdd(&gbase[t], h) : 0u;
    }
    __syncthreads();
    for (int p = lo + (int)threadIdx.x; p < hi; p += 1024) {
        float d = dist[p];
        if (d >= 12.0f) continue;
        uint32_t i = (uint32_t)idx_i[p];
        uint32_t b = i >> BSH;
        uint32_t pos = atomicAdd(&run[b], 1u);
        uint32_t packed = ((uint32_t)idx_j[p] & 0xFFFFu) | ((i & (BSZ - 1u)) << 16);
        recs[pos] = make_uint2(__float_as_uint(d), packed);
    }
}

// ---------------------------------------------------------------------------
// CN phase: one block per bucket, LDS accumulation, non-atomic global write.
__global__ __launch_bounds__(256) void cn_bucket(const uint2* __restrict__ recs,
                                                 const uint32_t* __restrict__ gstart,
                                                 const uint32_t* __restrict__ totals,
                                                 const float* __restrict__ rcovA,
                                                 float* __restrict__ cn,
                                                 int n_atoms) {
    __shared__ float lrc[BSZ];
    __shared__ float acc[BSZ];
    int b = blockIdx.x;
    int base_atom = b << BSH;
    for (int t = threadIdx.x; t < BSZ; t += 256) {
        int i = base_atom + t;
        lrc[t] = (i < n_atoms) ? rcovA[i] : 0.0f;
        acc[t] = 0.0f;
    }
    __syncthreads();
    uint32_t lo = gstart[b], n = totals[b];
    for (uint32_t k = threadIdx.x; k < n; k += 256) {
        uint2 r = recs[lo + k];
        float d = __uint_as_float(r.x);
        int j  = r.y & 0xFFFF;
        int il = r.y >> 16;
        float rij = lrc[il] + rcovA[j];
        float sw = switch_fn(d);
        float cnij = sw / (1.0f + expf(-16.0f * (rij / d - 1.0f)));
        atomicAdd(&acc[il], cnij);               // LDS atomic
    }
    __syncthreads();
    for (int t = threadIdx.x; t < BSZ; t += 256) {
        int i = base_atom + t;
        if (i < n_atoms) cn[i] = acc[t];
    }
}

// ---------------------------------------------------------------------------
__global__ __launch_bounds__(256) void atom_weights(const float* __restrict__ rcn,
                                                    const float* __restrict__ r2r4,
                                                    const int* __restrict__ Z,
                                                    const float* __restrict__ cn,
                                                    float* __restrict__ arec,
                                                    int n_atoms) {
    int i = blockIdx.x * blockDim.x + threadIdx.x;
    if (i >= n_atoms) return;
    int z = Z[i];
    float w[NREF];
    calc_weights(rcn + (size_t)z * NREF, cn[i], w);
    float4 v0 = make_float4(w[0], w[1], w[2], w[3]);
    float4 v1 = make_float4(w[4], r2r4[z], __int_as_float(z), 0.0f);
    float4* dst = (float4*)(arec + (size_t)i * 8);
    dst[0] = v0;
    dst[1] = v1;
}

// ---------------------------------------------------------------------------
// Energy phase: one block per bucket; i-side records served from LDS,
// j-side 2x float4 L2 gather, rc6 tile gather; LDS accumulation.
__global__ __launch_bounds__(256) void energy_bucket(const uint2* __restrict__ recs,
                                                     const uint32_t* __restrict__ gstart,
                                                     const uint32_t* __restrict__ totals,
                                                     const float* __restrict__ arec,
                                                     const float* __restrict__ rc6pad,
                                                     const float* __restrict__ s6p,
                                                     const float* __restrict__ s8p,
                                                     const float* __restrict__ a1p,
                                                     const float* __restrict__ a2p,
                                                     float* __restrict__ eout,
                                                     int n_atoms) {
    __shared__ float4 la0[BSZ];
    __shared__ float4 la1[BSZ];
    __shared__ float  acc[BSZ];
    int b = blockIdx.x;
    int base_atom = b << BSH;
    for (int t = threadIdx.x; t < BSZ; t += 256) {
        int i = min(base_atom + t, n_atoms - 1);
        const float4* A = (const float4*)(arec + (size_t)i * 8);
        la0[t] = A[0];
        la1[t] = A[1];
        acc[t] = 0.0f;
    }
    __syncthreads();
    float s6 = s6p[0], s8 = s8p[0], a1 = a1p[0], a2 = a2p[0];
    uint32_t lo = gstart[b], n = totals[b];
    for (uint32_t k = threadIdx.x; k < n; k += 256) {
        uint2 r = recs[lo + k];
        float d = __uint_as_float(r.x);
        int j  = r.y & 0xFFFF;
        int il = r.y >> 16;
        float4 ai0 = la0[il];
        float4 ai1 = la1[il];
        const float4* Aj = (const float4*)(arec + (size_t)j * 8);
        float4 aj0 = Aj[0];
        float4 aj1 = Aj[1];
        float wi[NREF] = {ai0.x, ai0.y, ai0.z, ai0.w, ai1.x};
        float wj[NREF] = {aj0.x, aj0.y, aj0.z, aj0.w, aj1.x};
        int zi = __float_as_int(ai1.z);
        int zj = __float_as_int(aj1.z);

        const float4* T4 = (const float4*)(rc6pad + (size_t)(zi * MAXZ + zj) * 32);
        float tt[25];
#pragma unroll
        for (int kk = 0; kk < 6; kk++) {
            float4 t = T4[kk];
            tt[4 * kk + 0] = t.x;
            if (4 * kk + 1 < 25) tt[4 * kk + 1] = t.y;
            if (4 * kk + 2 < 25) tt[4 * kk + 2] = t.z;
            if (4 * kk + 3 < 25) tt[4 * kk + 3] = t.w;
        }
        tt[24] = ((const float*)T4)[24];

        float c6 = 0.0f;
#pragma unroll
        for (int a = 0; a < NREF; a++) {
            float s = 0.0f;
#pragma unroll
            for (int bb = 0; bb < NREF; bb++) s = fmaf(wj[bb], tt[a * NREF + bb], s);
            c6 = fmaf(wi[a], s, c6);
        }

        float qq = 3.0f * ai1.y * aj1.y;
        float rr = a1 * sqrtf(qq) + a2;
        float d2 = d * d;
        float d6 = d2 * d2 * d2;
        float d8 = d6 * d2;
        float rr2 = rr * rr;
        float rr6 = rr2 * rr2 * rr2;
        float rr8 = rr6 * rr2;
        float sw = switch_fn(d);

        float e = -0.5f * (s6 * c6 / (d6 + rr6) + s8 * qq * c6 / (d8 + rr8)) * sw;
        atomicAdd(&acc[il], e);                  // LDS atomic
    }
    __syncthreads();
    for (int t = threadIdx.x; t < BSZ; t += 256) {
        int i = base_atom + t;
        if (i < n_atoms) eout[i] = acc[t];
    }
}

// ---------------------------------------------------------------------------
// Fallback (R5-proven) kernels: global-atomic scatter path.
__global__ __launch_bounds__(256) void pair_cn_g(const float* __restrict__ dist,
                                                 const float* __restrict__ rcovA,
                                                 const int* __restrict__ idx_i,
                                                 const int* __restrict__ idx_j,
                                                 float* __restrict__ cn,
                                                 int n_pairs) {
    int p = blockIdx.x * blockDim.x + threadIdx.x;
    if (p >= n_pairs) return;
    float d = dist[p];
    if (d >= 12.0f) return;
    int i = idx_i[p];
    int j = idx_j[p];
    float rij = rcovA[i] + rcovA[j];
    float sw = switch_fn(d);
    atomicAdd(&cn[i], sw / (1.0f + expf(-16.0f * (rij / d - 1.0f))));
}

__global__ __launch_bounds__(256) void pair_energy_g(const float* __restrict__ dist,
                                                     const int* __restrict__ idx_i,
                                                     const int* __restrict__ idx_j,
                                                     const float* __restrict__ arec,
                                                     const float* __restrict__ rc6pad,
                                                     const float* __restrict__ s6p,
                                                     const float* __restrict__ s8p,
                                                     const float* __restrict__ a1p,
                                                     const float* __restrict__ a2p,
                                                     float* __restrict__ eout,
                                                     int n_pairs) {
    int p = blockIdx.x * blockDim.x + threadIdx.x;
    if (p >= n_pairs) return;
    float d = dist[p];
    if (d >= 12.0f) return;
    int i = idx_i[p];
    int j = idx_j[p];
    const float4* Ai = (const float4*)(arec + (size_t)i * 8);
    const float4* Aj = (const float4*)(arec + (size_t)j * 8);
    float4 ai0 = Ai[0], ai1 = Ai[1], aj0 = Aj[0], aj1 = Aj[1];
    float wi[NREF] = {ai0.x, ai0.y, ai0.z, ai0.w, ai1.x};
    float wj[NREF] = {aj0.x, aj0.y, aj0.z, aj0.w, aj1.x};
    int zi = __float_as_int(ai1.z);
    int zj = __float_as_int(aj1.z);
    const float4* T4 = (const float4*)(rc6pad + (size_t)(zi * MAXZ + zj) * 32);
    float tt[25];
#pragma unroll
    for (int k = 0; k < 6; k++) {
        float4 t = T4[k];
        tt[4 * k + 0] = t.x;
        if (4 * k + 1 < 25) tt[4 * k + 1] = t.y;
        if (4 * k + 2 < 25) tt[4 * k + 2] = t.z;
        if (4 * k + 3 < 25) tt[4 * k + 3] = t.w;
    }
    tt[24] = ((const float*)T4)[24];
    float c6 = 0.0f;
#pragma unroll
    for (int a = 0; a < NREF; a++) {
        float s = 0.0f;
#pragma unroll
        for (int bb = 0; bb < NREF; bb++) s = fmaf(wj[bb], tt[a * NREF + bb], s);
        c6 = fmaf(wi[a], s, c6);
    }
    float qq = 3.0f * ai1.y * aj1.y;
    float rr = a1p[0] * sqrtf(qq) + a2p[0];
    float d2 = d * d;
    float d6 = d2 * d2 * d2;
    float d8 = d6 * d2;
    float rr2 = rr * rr;
    float rr6 = rr2 * rr2 * rr2;
    float rr8 = rr6 * rr2;
    float sw = switch_fn(d);
    float e = -0.5f * (s6p[0] * c6 / (d6 + rr6) + s8p[0] * qq * c6 / (d8 + rr8)) * sw;
    atomicAdd(&eout[i], e);
}

// ---------------------------------------------------------------------------
extern "C" void kernel_launch(void* const* d_in, const int* in_sizes, int n_in,
                              void* d_out, int out_size, void* d_ws, size_t ws_size,
                              hipStream_t stream) {
    const float* dist = (const float*)d_in[0];
    const float* rcov = (const float*)d_in[1];
    const float* rcn  = (const float*)d_in[2];
    const float* rc6  = (const float*)d_in[3];
    const float* r2r4 = (const float*)d_in[4];
    const float* s6p  = (const float*)d_in[5];
    const float* s8p  = (const float*)d_in[6];
    const float* a1p  = (const float*)d_in[7];
    const float* a2p  = (const float*)d_in[8];
    const int* Z    = (const int*)d_in[9];
    const int* idxi = (const int*)d_in[10];
    const int* idxj = (const int*)d_in[11];
    float* out = (float*)d_out;

    int n_pairs = in_sizes[0];
    int n_atoms = in_sizes[9];
    int agrid = (n_atoms + 255) / 256;
    int pgrid = (n_pairs + 255) / 256;
    int rc_total = MAXZ * MAXZ * 32;
    size_t rc_bytes = (size_t)rc_total * 4;

    char* ws = (char*)d_ws;

    // fast-path workspace layout
    size_t o_totals = 0;                           // NB u32
    size_t o_gstart = 2048;                        // NB u32
    size_t o_gbase  = 4096;                        // NB u32
    size_t o_cn     = 8192;                        // n_atoms f32
    size_t o_rcovA  = o_cn + (size_t)n_atoms * 4;
    size_t o_arec   = o_rcovA + (size_t)n_atoms * 4;
    size_t o_rc6    = o_arec + (size_t)n_atoms * 32;
    size_t o_recs   = (o_rc6 + rc_bytes + 255) & ~(size_t)255;
    size_t need_fast = o_recs + (size_t)n_pairs * 8;

    bool fast = (ws_size >= need_fast) && (n_atoms <= 65536);

    if (fast) {
        uint32_t* totals = (uint32_t*)(ws + o_totals);
        uint32_t* gstart = (uint32_t*)(ws + o_gstart);
        uint32_t* gbase  = (uint32_t*)(ws + o_gbase);
        float* cn     = (float*)(ws + o_cn);
        float* rcovA  = (float*)(ws + o_rcovA);
        float* arec   = (float*)(ws + o_arec);
        float* rcpad  = (float*)(ws + o_rc6);
        uint2* recs   = (uint2*)(ws + o_recs);

        hipMemsetAsync(totals, 0, NB * 4, stream);
        prep_rcov<<<agrid, 256, 0, stream>>>(rcov, Z, rcovA, n_atoms);
        repack_rc6<<<(rc_total + 255) / 256, 256, 0, stream>>>(rc6, rcpad, rc_total);

        int sblocks = 256;
        int chunk = (n_pairs + sblocks - 1) / sblocks;
        count_pairs<<<sblocks, 1024, 0, stream>>>(dist, idxi, totals, n_pairs, chunk);
        scan_buckets<<<1, NB, 0, stream>>>(totals, gstart, gbase);
        scatter_pairs<<<sblocks, 1024, 0, stream>>>(dist, idxi, idxj, gbase, recs,
                                                    n_pairs, chunk);
        cn_bucket<<<NB, 256, 0, stream>>>(recs, gstart, totals, rcovA, cn, n_atoms);
        atom_weights<<<agrid, 256, 0, stream>>>(rcn, r2r4, Z, cn, arec, n_atoms);
        energy_bucket<<<NB, 256, 0, stream>>>(recs, gstart, totals, arec, rcpad,
                                              s6p, s8p, a1p, a2p, out, n_atoms);
    } else {
        // R5-proven fallback: global-atomic path
        float* cn    = (float*)ws;
        float* rcovA = (float*)(ws + (size_t)n_atoms * 4);
        float* arec  = (float*)(ws + (size_t)n_atoms * 8);
        float* rcpad = (float*)(ws + (size_t)n_atoms * 40);
        hipMemsetAsync(out, 0, (size_t)n_atoms * 4, stream);
        hipMemsetAsync(cn, 0, (size_t)n_atoms * 4, stream);
        prep_rcov<<<agrid, 256, 0, stream>>>(rcov, Z, rcovA, n_atoms);
        repack_rc6<<<(rc_total + 255) / 256, 256, 0, stream>>>(rc6, rcpad, rc_total);
        pair_cn_g<<<pgrid, 256, 0, stream>>>(dist, rcovA, idxi, idxj, cn, n_pairs);
        atom_weights<<<agrid, 256, 0, stream>>>(rcn, r2r4, Z, cn, arec, n_atoms);
        pair_energy_g<<<pgrid, 256, 0, stream>>>(dist, idxi, idxj, arec, rcpad,
                                                 s6p, s8p, a1p, a2p, out, n_pairs);
    }
}